// Round 13
// baseline (1911.587 us; speedup 1.0000x reference)
//
#include <hip/hip_runtime.h>
#include <cstdint>

typedef float f32x4 __attribute__((ext_vector_type(4)));
typedef __bf16 bf16x8 __attribute__((ext_vector_type(8)));
typedef unsigned short us8 __attribute__((ext_vector_type(8)));
typedef unsigned int u32x4 __attribute__((ext_vector_type(4)));

#define T2 126

__device__ __forceinline__ unsigned short f2bf(float x){
  union { float f; uint32_t u; } v; v.f = x;
  return (unsigned short)((v.u + 0x7fffu + ((v.u >> 16) & 1u)) >> 16);
}
__device__ __forceinline__ float bf2f(unsigned short h){
  union { uint32_t u; float f; } v; v.u = ((uint32_t)h) << 16; return v.f;
}
__device__ __forceinline__ f32x4 mfma_bf16(us8 a, us8 b, f32x4 c){
  return __builtin_amdgcn_mfma_f32_16x16x32_bf16(
      __builtin_bit_cast(bf16x8, a), __builtin_bit_cast(bf16x8, b), c, 0, 0, 0);
}
__device__ __forceinline__ float sigm(float x){ return 1.0f / (1.0f + __expf(-x)); }

// XOR-swizzled LDS address for a [rows][512] bf16 tile, 8-short (16B) chunks.
#define HSWZ(row, chunk) ((row) * 512 + ((((chunk) ^ ((row) & 7))) << 3))

// ---------------------------------------------------------------------------
// Pack (1536,512) fp32 weights -> bf16 MFMA B-fragments.
// Tile (jt,kt): lane l elem e holds W[16jt+(l&15)][32kt+8*(l>>4)+e]
// ---------------------------------------------------------------------------
__global__ void __launch_bounds__(256) pack_w_kernel(const float* __restrict__ w,
                                                     unsigned short* __restrict__ dst){
  int tid = blockIdx.x * 256 + threadIdx.x;     // 0..98303
  int l = tid & 63;
  int tile = tid >> 6;                          // jt*16 + kt
  int kt = tile & 15, jt = tile >> 4;
  int row = jt * 16 + (l & 15);
  int col = kt * 32 + (l >> 4) * 8;
  const float* s = w + (size_t)row * 512 + col;
  unsigned short o[8];
  #pragma unroll
  for (int e = 0; e < 8; e++) o[e] = f2bf(s[e]);
  *(us8*)(dst + (size_t)tid * 8) = *(const us8*)o;
}

// ---------------------------------------------------------------------------
// Per-launch init: hq parity0 = h(0) = 0; all tags = 0 (parity1 data is
// always written in-launch before its tag allows reading it).
// ---------------------------------------------------------------------------
__global__ void __launch_bounds__(256) scan_init_kernel(u32x4* __restrict__ hq,
                                                        unsigned int* __restrict__ tagbuf){
  int tid = blockIdx.x * 256 + threadIdx.x;
  int stride = gridDim.x * 256;
  for (int i = tid; i < 32768; i += stride)
    hq[i] = (u32x4){0u, 0u, 0u, 0u};
  for (int i = tid; i < 2 * 8 * 32 * 16; i += stride)
    tagbuf[i] = 0u;
}

// ---------------------------------------------------------------------------
// FULLY-FUSED weight-stationary persistent GRU pipeline.
// Grid = 256 blocks = 32 batch-groups (16 rows) x 8 hidden-slices (64 cols).
// Handoff protocol = round-10 (proven): quad-granular sc0+sc1 exchange,
// per-line tags, publish->drain->barrier->tag, poll->barrier->stage.
// NEW: conv+GELU+gates-GEMM for step s+1 run in the handoff shadow (before
// the poll, off the inter-block dependency chain), into ping-pong LDS gbuf.
// wih B-frags streamed from L2 (~30% of per-XCD L2 BW); whh pinned in regs.
// Deconv emit also in shadow (as before). No gates/outs global buffers, no
// chunking, one scan dispatch for all 126 steps.
// ---------------------------------------------------------------------------
__global__ void __launch_bounds__(256, 1) gru_scan_kernel(
    const unsigned short* __restrict__ whh_p,
    const unsigned short* __restrict__ wih_p,
    const float* __restrict__ b_hh,
    const float* __restrict__ b_ih,
    u32x4* __restrict__ hq,                // [2][512][64] quads
    unsigned int* __restrict__ tagbuf,     // [2][8][32] x 16 u32 (64B stride)
    const float* __restrict__ frames,
    const float* __restrict__ cw,
    const float* __restrict__ cb,
    const float* __restrict__ dw,
    const float* __restrict__ db,
    float* __restrict__ out){
  __shared__ unsigned short hlds[16 * 512];       // h(s) slab, swizzled
  __shared__ unsigned short featl[16 * 512];      // feat(s+1), swizzled
  __shared__ unsigned short gbuf[2][3 * 16 * 72]; // gates ping-pong (padded 72)
  __shared__ unsigned short hout[16 * 64];        // block's h(s+1) tile
  __shared__ float wl[1024];                      // conv weights
  __shared__ float dwl[512];                      // deconv weights
  __shared__ float cbl[32];                       // conv bias
  const int tid = threadIdx.x;
  const int B = blockIdx.x;
  const int grp = B & 31;                     // batch group 0..31
  const int slc = B >> 5;                     // hidden slice 0..7
  const int l = tid & 63;
  const int w = tid >> 6;                     // wave 0..3
  const int lr = l & 15, lh = l >> 4;
  const int j = slc * 64 + w * 16 + lr;       // hidden col
  const int rowb = grp * 16;                  // batch row base
  const int rloc = lh * 4;                    // + r = local row

  dwl[tid] = dw[tid]; dwl[tid + 256] = dw[tid + 256];
  wl[tid] = cw[tid]; wl[tid + 256] = cw[tid + 256];
  wl[tid + 512] = cw[tid + 512]; wl[tid + 768] = cw[tid + 768];
  if (tid < 32) cbl[tid] = cb[tid];
  const float dbias = db[0];

  // persistent w_hh fragments, pinned via volatile loads
  us8 wr[16], wz[16], wn[16];
  {
    const int jt = slc * 4 + w;
    #pragma unroll
    for (int kt = 0; kt < 16; kt++){
      wr[kt] = *(volatile const us8*)(whh_p + ((size_t)((jt      ) * 16 + kt) * 512 + l * 8));
      wz[kt] = *(volatile const us8*)(whh_p + ((size_t)((jt + 32) * 16 + kt) * 512 + l * 8));
      wn[kt] = *(volatile const us8*)(whh_p + ((size_t)((jt + 64) * 16 + kt) * 512 + l * 8));
    }
  }
  const float bhr = b_hh[j], bhz = b_hh[512 + j], bhn = b_hh[1024 + j];

  // gates-GEMM per-thread tile constants: wave w owns block j-tiles q=w*3..w*3+2
  // (block cols = 3 gates x 64; q -> gate g=q>>2, col-tile wt=q&3)
  int jtg[3], gg[3], wtt[3]; float gbias[3];
  #pragma unroll
  for (int jj = 0; jj < 3; jj++){
    int q = w * 3 + jj; gg[jj] = q >> 2; wtt[jj] = q & 3;
    jtg[jj] = gg[jj] * 32 + slc * 4 + wtt[jj];            // global j-tile in wih_p
    gbias[jj] = b_ih[gg[jj] * 512 + slc * 64 + wtt[jj] * 16 + lr];
  }
  float hprev[4] = {0.0f, 0.0f, 0.0f, 0.0f};
  __syncthreads();                  // wl/cbl/dwl ready

  // conv+GELU for feat(u) -> featl (one task per thread: sample i, patch)
  auto convgelu = [&](int u){
    int i = tid >> 4, patch = tid & 15;
    const float* fb = frames + ((size_t)(rowb + i) * 128 + u) * 256;
    int ii = patch >> 2, jjp = patch & 3;
    float4 pv[4], cv[4];
    #pragma unroll
    for (int p = 0; p < 4; p++){
      int base = (ii * 4 + p) * 16 + jjp * 4;
      pv[p] = *(const float4*)(fb + base);          // prev = frame u
      cv[p] = *(const float4*)(fb + 256 + base);    // curr = frame u+1
    }
    #pragma unroll
    for (int o = 0; o < 32; o++){
      const float* wc = &wl[o * 32];
      float acc = cbl[o];
      #pragma unroll
      for (int p = 0; p < 4; p++){
        acc += cv[p].x * wc[p*4+0] + cv[p].y * wc[p*4+1]
             + cv[p].z * wc[p*4+2] + cv[p].w * wc[p*4+3];
        acc += pv[p].x * wc[16+p*4+0] + pv[p].y * wc[16+p*4+1]
             + pv[p].z * wc[16+p*4+2] + pv[p].w * wc[16+p*4+3];
      }
      float g = 0.5f * acc * (1.0f + erff(acc * 0.70710678118654752f));
      int col = o * 16 + patch;
      featl[HSWZ(i, col >> 3) + (col & 7)] = f2bf(g);
    }
  };

  // gates GEMM: featl (LDS) @ wih^T (L2-streamed) + b_ih -> gbuf[par]
  auto gatesgemm = [&](int par){
    f32x4 a0 = {0.f,0.f,0.f,0.f}, a1 = {0.f,0.f,0.f,0.f}, a2 = {0.f,0.f,0.f,0.f};
    #pragma unroll
    for (int kt = 0; kt < 16; kt++){
      us8 a = *(const us8*)&featl[HSWZ(lr, kt * 4 + lh)];
      us8 b0 = *(const us8*)(wih_p + ((size_t)(jtg[0] * 16 + kt) * 512 + l * 8));
      us8 b1 = *(const us8*)(wih_p + ((size_t)(jtg[1] * 16 + kt) * 512 + l * 8));
      us8 b2 = *(const us8*)(wih_p + ((size_t)(jtg[2] * 16 + kt) * 512 + l * 8));
      a0 = mfma_bf16(a, b0, a0);
      a1 = mfma_bf16(a, b1, a1);
      a2 = mfma_bf16(a, b2, a2);
    }
    unsigned short* gb = &gbuf[par][0];
    #pragma unroll
    for (int r = 0; r < 4; r++){
      gb[(gg[0] * 16 + lh * 4 + r) * 72 + wtt[0] * 16 + lr] = f2bf(a0[r] + gbias[0]);
      gb[(gg[1] * 16 + lh * 4 + r) * 72 + wtt[1] * 16 + lr] = f2bf(a1[r] + gbias[1]);
      gb[(gg[2] * 16 + lh * 4 + r) * 72 + wtt[2] * 16 + lr] = f2bf(a2[r] + gbias[2]);
    }
  };

  // poll 8 per-line tags for step s (parity s&1), then barrier
  auto poll = [&](int s){
    if (tid < 8){
      const unsigned int* tp = tagbuf + (((size_t)(s & 1) * 8 + tid) * 32 + grp) * 16;
      unsigned int want = (unsigned)s;
      unsigned int tv;
      for (;;){
        asm volatile("global_load_dword %0, %1, off sc0 sc1\n\ts_waitcnt vmcnt(0)"
                     : "=&v"(tv) : "v"(tp) : "memory");
        if (tv >= want) break;
        __builtin_amdgcn_s_sleep(1);
      }
    }
    __syncthreads();
  };

  // stage h(s) slab (16 rows x 64 quads) -> hlds, 4 quads/thread
  auto stage = [&](int s){
    const u32x4* rb = hq + (size_t)(s & 1) * 32768;
    int quad = tid & 63, r0 = tid >> 6;       // r0 0..3
    const u32x4* p0 = rb + ((size_t)(rowb + r0) * 64 + quad);
    const u32x4* p1 = p0 + 4 * 64;
    const u32x4* p2 = p0 + 8 * 64;
    const u32x4* p3 = p0 + 12 * 64;
    u32x4 q0, q1, q2, q3;
    asm volatile(
      "global_load_dwordx4 %0, %4, off sc0 sc1\n\t"
      "global_load_dwordx4 %1, %5, off sc0 sc1\n\t"
      "global_load_dwordx4 %2, %6, off sc0 sc1\n\t"
      "global_load_dwordx4 %3, %7, off sc0 sc1\n\t"
      "s_waitcnt vmcnt(0)"
      : "=&v"(q0), "=&v"(q1), "=&v"(q2), "=&v"(q3)
      : "v"(p0), "v"(p1), "v"(p2), "v"(p3)
      : "memory");
    *(u32x4*)&hlds[HSWZ(r0,      quad)] = q0;
    *(u32x4*)&hlds[HSWZ(r0 + 4,  quad)] = q1;
    *(u32x4*)&hlds[HSWZ(r0 + 8,  quad)] = q2;
    *(u32x4*)&hlds[HSWZ(r0 + 12, quad)] = q3;
    __syncthreads();
  };

  // fused deconv: out[:, so] from hlds (= h(so+1)); residual frames[b][so+1]
  auto emit = [&](int so){
    int row = tid >> 4;                       // sample row 0..15
    int b = rowb + row;
    const float* fr = frames + ((size_t)b * 128 + so + 1) * 256;
    float* ob = out + ((size_t)b * T2 + so) * 256;
    #pragma unroll
    for (int e = 0; e < 2; e++){
      int pi = (tid & 15) * 2 + e;            // 0..31
      int pr = slc * 2 + (pi >> 4), pc = pi & 15;
      int ii = pr >> 2, pp = pr & 3, jj2 = pc >> 2, qq = pc & 3;
      float acc = dbias;
      #pragma unroll
      for (int c = 0; c < 32; c++){
        int ch = c * 16 + ii * 4 + jj2;
        acc += bf2f(hlds[HSWZ(row, ch >> 3) + (ch & 7)]) * dwl[c * 16 + pp * 4 + qq];
      }
      float dlt = tanhf(acc);
      float rv = fr[pr * 16 + pc] + dlt;
      ob[pr * 16 + pc] = fminf(fmaxf(rv, 0.0f), 1.0f);
    }
  };

  // prologue: gates(0) into gbuf[0]
  convgelu(0);
  __syncthreads();
  gatesgemm(0);

  for (int s = 0; s < T2; s++){
    // ---- shadow work: gates(s+1) (off the inter-block dependency chain) ----
    if (s + 1 < T2){
      __syncthreads();               // WAR: featl vs gatesgemm(s) reads
      convgelu(s + 1);
      __syncthreads();               // featl ready
      gatesgemm((s + 1) & 1);
    }
    // ---- critical chain: r10 protocol verbatim ----
    poll(s);                         // barrier inside (also WAR: hlds/hout)
    stage(s);
    f32x4 aR = {0.f,0.f,0.f,0.f}, aZ = {0.f,0.f,0.f,0.f}, aN = {0.f,0.f,0.f,0.f};
    #pragma unroll
    for (int kt = 0; kt < 16; kt++){
      us8 a = *(const us8*)&hlds[HSWZ(lr, kt * 4 + lh)];
      aR = mfma_bf16(a, wr[kt], aR);
      aZ = mfma_bf16(a, wz[kt], aZ);
      aN = mfma_bf16(a, wn[kt], aN);
    }
    const unsigned short* gb = &gbuf[s & 1][0];
    #pragma unroll
    for (int r = 0; r < 4; r++){
      float gxr = bf2f(gb[(      rloc + r) * 72 + w * 16 + lr]);
      float gxz = bf2f(gb[(16 + rloc + r) * 72 + w * 16 + lr]);
      float gxn = bf2f(gb[(32 + rloc + r) * 72 + w * 16 + lr]);
      float rr = sigm(gxr + aR[r] + bhr);
      float zz = sigm(gxz + aZ[r] + bhz);
      float nn = tanhf(gxn + rr * (aN[r] + bhn));
      float hv = (1.0f - zz) * nn + zz * hprev[r];
      hprev[r] = hv;
      hout[(rloc + r) * 64 + w * 16 + lr] = f2bf(hv);
    }
    __syncthreads();                 // hout ready
    if (tid < 128){
      int row = tid >> 3, q = tid & 7;
      u32x4 hv = *(const u32x4*)&hout[row * 64 + q * 8];
      u32x4* dst = hq + ((size_t)(((s + 1) & 1) * 512 + rowb + row) * 64 + slc * 8 + q);
      asm volatile("global_store_dwordx4 %0, %1, off sc0 sc1" :: "v"(dst), "v"(hv) : "memory");
    }
    asm volatile("s_waitcnt vmcnt(0)" ::: "memory");   // data drain (per wave)
    __syncthreads();                                   // all waves drained
    if (tid == 0){
      unsigned int tg = (unsigned)(s + 1);
      unsigned int* tp = tagbuf + (((size_t)((s + 1) & 1) * 8 + slc) * 32 + grp) * 16;
      asm volatile("global_store_dword %0, %1, off sc0 sc1" :: "v"(tp), "v"(tg) : "memory");
    }
    // fused deconv for out[:, s-1] — in the handoff shadow
    if (s >= 1) emit(s - 1);
  }
  // final output t=125 from h(126)
  poll(T2);                          // barrier also WAR-protects hlds vs last emit
  stage(T2);
  emit(T2 - 1);
}

extern "C" void kernel_launch(void* const* d_in, const int* in_sizes, int n_in,
                              void* d_out, int out_size, void* d_ws, size_t ws_size,
                              hipStream_t stream) {
  const float* frames   = (const float*)d_in[0];
  const float* conv_w   = (const float*)d_in[1];
  const float* conv_b   = (const float*)d_in[2];
  const float* w_ih     = (const float*)d_in[3];
  const float* w_hh     = (const float*)d_in[4];
  const float* b_ih     = (const float*)d_in[5];
  const float* b_hh     = (const float*)d_in[6];
  const float* deconv_w = (const float*)d_in[7];
  const float* deconv_b = (const float*)d_in[8];
  float* out = (float*)d_out;
  char* ws = (char*)d_ws;

  // fixed workspace: wih_p 1.5M | whh_p 1.5M | hq 1M | tagbuf 32K  (~4.1 MB)
  unsigned short* wih_p  = (unsigned short*)(ws);
  unsigned short* whh_p  = (unsigned short*)(ws + 1572864LL);
  u32x4*          hq     = (u32x4*)         (ws + 3145728LL);
  unsigned int*   tagbuf = (unsigned int*)  (ws + 4194304LL);

  pack_w_kernel<<<384, 256, 0, stream>>>(w_ih, wih_p);
  pack_w_kernel<<<384, 256, 0, stream>>>(w_hh, whh_p);
  scan_init_kernel<<<64, 256, 0, stream>>>(hq, tagbuf);
  gru_scan_kernel<<<256, 256, 0, stream>>>(whh_p, wih_p, b_hh, b_ih, hq, tagbuf,
                                           frames, conv_w, conv_b,
                                           deconv_w, deconv_b, out);
}

// Round 14
// 1010.420 us; speedup vs baseline: 1.8919x; 1.8919x over previous
//
#include <hip/hip_runtime.h>
#include <cstdint>

typedef float f32x4 __attribute__((ext_vector_type(4)));
typedef __bf16 bf16x8 __attribute__((ext_vector_type(8)));
typedef unsigned short us8 __attribute__((ext_vector_type(8)));
typedef unsigned int u32x4 __attribute__((ext_vector_type(4)));

#define T2 126

__device__ __forceinline__ unsigned short f2bf(float x){
  union { float f; uint32_t u; } v; v.f = x;
  return (unsigned short)((v.u + 0x7fffu + ((v.u >> 16) & 1u)) >> 16);
}
__device__ __forceinline__ float bf2f(unsigned short h){
  union { uint32_t u; float f; } v; v.u = ((uint32_t)h) << 16; return v.f;
}
__device__ __forceinline__ f32x4 mfma_bf16(us8 a, us8 b, f32x4 c){
  return __builtin_amdgcn_mfma_f32_16x16x32_bf16(
      __builtin_bit_cast(bf16x8, a), __builtin_bit_cast(bf16x8, b), c, 0, 0, 0);
}
__device__ __forceinline__ float sigm(float x){ return 1.0f / (1.0f + __expf(-x)); }

// XOR-swizzled LDS address for a [rows][512] bf16 tile, 8-short (16B) chunks.
#define HSWZ(row, chunk) ((row) * 512 + ((((chunk) ^ ((row) & 7))) << 3))

// ---------------------------------------------------------------------------
// Pack (1536,512) fp32 weights -> bf16 MFMA B-fragments.
// Tile (jt,kt): lane l elem e holds W[16jt+(l&15)][32kt+8*(l>>4)+e]
// ---------------------------------------------------------------------------
__global__ void __launch_bounds__(256) pack_w_kernel(const float* __restrict__ w,
                                                     unsigned short* __restrict__ dst){
  int tid = blockIdx.x * 256 + threadIdx.x;     // 0..98303
  int l = tid & 63;
  int tile = tid >> 6;                          // jt*16 + kt
  int kt = tile & 15, jt = tile >> 4;
  int row = jt * 16 + (l & 15);
  int col = kt * 32 + (l >> 4) * 8;
  const float* s = w + (size_t)row * 512 + col;
  unsigned short o[8];
  #pragma unroll
  for (int e = 0; e < 8; e++) o[e] = f2bf(s[e]);
  *(us8*)(dst + (size_t)tid * 8) = *(const us8*)o;
}

// ---------------------------------------------------------------------------
// Patchify conv + bias + exact GELU for ALL timesteps -> featg bf16
// layout [t][b][512] (so the scan stages a group's 16 rows contiguously).
// One sample per block (256 thr, 2 outputs each). erff lives HERE, off the
// scan's critical chain.
// ---------------------------------------------------------------------------
__global__ void __launch_bounds__(256) conv_gelu_kernel(const float* __restrict__ frames,
                                                        const float* __restrict__ cw,
                                                        const float* __restrict__ cb,
                                                        unsigned short* __restrict__ featg){
  __shared__ float im[512];
  __shared__ float wl[1024];
  int n = blockIdx.x;              // t*512 + b
  int t = n >> 9, b = n & 511;
  const float* fr = frames + ((size_t)b * 128 + t) * 256;
  int tid = threadIdx.x;
  ((float2*)im)[tid] = ((const float2*)fr)[tid];   // frames t (prev) | t+1 (curr)
  #pragma unroll
  for (int i = 0; i < 4; i++) wl[tid + 256 * i] = cw[tid + 256 * i];
  __syncthreads();
  #pragma unroll
  for (int half = 0; half < 2; half++){
    int oi = tid + half * 256;
    int o = oi >> 4, ii = (oi >> 2) & 3, jj = oi & 3;
    const float* wc = &wl[o * 32];
    float s = cb[o];
    #pragma unroll
    for (int p = 0; p < 4; p++)
      #pragma unroll
      for (int q = 0; q < 4; q++){
        int pix = (ii * 4 + p) * 16 + jj * 4 + q;
        s += im[256 + pix] * wc[p * 4 + q] + im[pix] * wc[16 + p * 4 + q];
      }
    float g = 0.5f * s * (1.0f + erff(s * 0.70710678118654752f));
    featg[(size_t)n * 512 + oi] = f2bf(g);
  }
}

// ---------------------------------------------------------------------------
// Per-launch init: hq parity0 = h(0) = 0; all tags = 0.
// ---------------------------------------------------------------------------
__global__ void __launch_bounds__(256) scan_init_kernel(u32x4* __restrict__ hq,
                                                        unsigned int* __restrict__ tagbuf){
  int tid = blockIdx.x * 256 + threadIdx.x;
  int stride = gridDim.x * 256;
  for (int i = tid; i < 32768; i += stride)
    hq[i] = (u32x4){0u, 0u, 0u, 0u};
  for (int i = tid; i < 2 * 8 * 32 * 16; i += stride)
    tagbuf[i] = 0u;
}

// ---------------------------------------------------------------------------
// Weight-stationary persistent GRU scan + shadow gates-GEMM + fused deconv.
// Grid = 256 blocks = 32 batch-groups (16 rows) x 8 hidden-slices (64 cols).
// Handoff protocol = round-10 verbatim (proven 645us): quad sc0+sc1
// exchange, per-line tags, publish->drain->barrier->tag, poll->barrier->
// stage. Shadow work per step (BEFORE the poll, off the inter-block chain):
// stage feat(s+1) (16KB, L3) -> LDS; gates-GEMM (48 MFMA, wih B-frags
// streamed from L2) -> ping-pong LDS gbuf. No gates global buffer, no
// chunking, no separate gemm kernel. r13's failure (in-loop conv: 8x
// duplicated erff VALU storm + LDS conflicts) is evicted to conv_gelu.
// ---------------------------------------------------------------------------
__global__ void __launch_bounds__(256, 1) gru_scan_kernel(
    const unsigned short* __restrict__ whh_p,
    const unsigned short* __restrict__ wih_p,
    const float* __restrict__ b_hh,
    const float* __restrict__ b_ih,
    u32x4* __restrict__ hq,                // [2][512][64] quads
    unsigned int* __restrict__ tagbuf,     // [2][8][32] x 16 u32 (64B stride)
    const unsigned short* __restrict__ featg,  // [126][512][512]
    const float* __restrict__ frames,
    const float* __restrict__ dw,
    const float* __restrict__ db,
    float* __restrict__ out){
  __shared__ unsigned short hlds[16 * 512];       // h(s) slab, swizzled
  __shared__ unsigned short featl[16 * 512];      // feat(s+1), swizzled
  __shared__ unsigned short gbuf[2][3 * 16 * 72]; // gates ping-pong (padded 72)
  __shared__ unsigned short hout[16 * 64];        // block's h(s+1) tile
  __shared__ float dwl[512];                      // deconv weights
  const int tid = threadIdx.x;
  const int B = blockIdx.x;
  const int grp = B & 31;                     // batch group 0..31
  const int slc = B >> 5;                     // hidden slice 0..7
  const int l = tid & 63;
  const int w = tid >> 6;                     // wave 0..3
  const int lr = l & 15, lh = l >> 4;
  const int j = slc * 64 + w * 16 + lr;       // hidden col
  const int rowb = grp * 16;                  // batch row base
  const int rloc = lh * 4;                    // + r = local row

  dwl[tid] = dw[tid]; dwl[tid + 256] = dw[tid + 256];
  const float dbias = db[0];

  // persistent w_hh fragments, pinned via volatile loads
  us8 wr[16], wz[16], wn[16];
  {
    const int jt = slc * 4 + w;
    #pragma unroll
    for (int kt = 0; kt < 16; kt++){
      wr[kt] = *(volatile const us8*)(whh_p + ((size_t)((jt      ) * 16 + kt) * 512 + l * 8));
      wz[kt] = *(volatile const us8*)(whh_p + ((size_t)((jt + 32) * 16 + kt) * 512 + l * 8));
      wn[kt] = *(volatile const us8*)(whh_p + ((size_t)((jt + 64) * 16 + kt) * 512 + l * 8));
    }
  }
  const float bhr = b_hh[j], bhz = b_hh[512 + j], bhn = b_hh[1024 + j];

  // shadow-gemm per-thread tile constants: wave w owns q = w*3..w*3+2
  // (q -> gate gg=q>>2, col-tile wtt=q&3; bijective over 12)
  int jtg[3], gg[3], wtt[3]; float gbias[3];
  #pragma unroll
  for (int jj = 0; jj < 3; jj++){
    int q = w * 3 + jj; gg[jj] = q >> 2; wtt[jj] = q & 3;
    jtg[jj] = gg[jj] * 32 + slc * 4 + wtt[jj];            // global j-tile in wih_p
    gbias[jj] = b_ih[gg[jj] * 512 + slc * 64 + wtt[jj] * 16 + lr];
  }
  float hprev[4] = {0.0f, 0.0f, 0.0f, 0.0f};
  __syncthreads();                  // dwl ready

  // stage feat(u) 16 rows (16KB, linear global) -> featl (swizzled)
  auto stagefeat = [&](int u){
    const u32x4* rb = (const u32x4*)(featg + (size_t)u * 512 * 512);
    int quad = tid & 63, r0 = tid >> 6;       // r0 0..3
    const u32x4* p0 = rb + ((size_t)(rowb + r0) * 64 + quad);
    u32x4 q0 = p0[0];
    u32x4 q1 = p0[4 * 64];
    u32x4 q2 = p0[8 * 64];
    u32x4 q3 = p0[12 * 64];
    *(u32x4*)&featl[HSWZ(r0,      quad)] = q0;
    *(u32x4*)&featl[HSWZ(r0 + 4,  quad)] = q1;
    *(u32x4*)&featl[HSWZ(r0 + 8,  quad)] = q2;
    *(u32x4*)&featl[HSWZ(r0 + 12, quad)] = q3;
    __syncthreads();
  };

  // gates GEMM: featl (LDS) @ wih^T (L2-streamed) + b_ih -> gbuf[par]
  auto gatesgemm = [&](int par){
    f32x4 a0 = {0.f,0.f,0.f,0.f}, a1 = {0.f,0.f,0.f,0.f}, a2 = {0.f,0.f,0.f,0.f};
    #pragma unroll
    for (int kt = 0; kt < 16; kt++){
      us8 a = *(const us8*)&featl[HSWZ(lr, kt * 4 + lh)];
      us8 b0 = *(const us8*)(wih_p + ((size_t)(jtg[0] * 16 + kt) * 512 + l * 8));
      us8 b1 = *(const us8*)(wih_p + ((size_t)(jtg[1] * 16 + kt) * 512 + l * 8));
      us8 b2 = *(const us8*)(wih_p + ((size_t)(jtg[2] * 16 + kt) * 512 + l * 8));
      a0 = mfma_bf16(a, b0, a0);
      a1 = mfma_bf16(a, b1, a1);
      a2 = mfma_bf16(a, b2, a2);
    }
    unsigned short* gb = &gbuf[par][0];
    #pragma unroll
    for (int r = 0; r < 4; r++){
      gb[(gg[0] * 16 + lh * 4 + r) * 72 + wtt[0] * 16 + lr] = f2bf(a0[r] + gbias[0]);
      gb[(gg[1] * 16 + lh * 4 + r) * 72 + wtt[1] * 16 + lr] = f2bf(a1[r] + gbias[1]);
      gb[(gg[2] * 16 + lh * 4 + r) * 72 + wtt[2] * 16 + lr] = f2bf(a2[r] + gbias[2]);
    }
  };

  // poll 8 per-line tags for step s (parity s&1), then barrier
  auto poll = [&](int s){
    if (tid < 8){
      const unsigned int* tp = tagbuf + (((size_t)(s & 1) * 8 + tid) * 32 + grp) * 16;
      unsigned int want = (unsigned)s;
      unsigned int tv;
      for (;;){
        asm volatile("global_load_dword %0, %1, off sc0 sc1\n\ts_waitcnt vmcnt(0)"
                     : "=&v"(tv) : "v"(tp) : "memory");
        if (tv >= want) break;
        __builtin_amdgcn_s_sleep(1);
      }
    }
    __syncthreads();
  };

  // stage h(s) slab (16 rows x 64 quads) -> hlds, 4 quads/thread
  auto stage = [&](int s){
    const u32x4* rb = hq + (size_t)(s & 1) * 32768;
    int quad = tid & 63, r0 = tid >> 6;       // r0 0..3
    const u32x4* p0 = rb + ((size_t)(rowb + r0) * 64 + quad);
    const u32x4* p1 = p0 + 4 * 64;
    const u32x4* p2 = p0 + 8 * 64;
    const u32x4* p3 = p0 + 12 * 64;
    u32x4 q0, q1, q2, q3;
    asm volatile(
      "global_load_dwordx4 %0, %4, off sc0 sc1\n\t"
      "global_load_dwordx4 %1, %5, off sc0 sc1\n\t"
      "global_load_dwordx4 %2, %6, off sc0 sc1\n\t"
      "global_load_dwordx4 %3, %7, off sc0 sc1\n\t"
      "s_waitcnt vmcnt(0)"
      : "=&v"(q0), "=&v"(q1), "=&v"(q2), "=&v"(q3)
      : "v"(p0), "v"(p1), "v"(p2), "v"(p3)
      : "memory");
    *(u32x4*)&hlds[HSWZ(r0,      quad)] = q0;
    *(u32x4*)&hlds[HSWZ(r0 + 4,  quad)] = q1;
    *(u32x4*)&hlds[HSWZ(r0 + 8,  quad)] = q2;
    *(u32x4*)&hlds[HSWZ(r0 + 12, quad)] = q3;
    __syncthreads();
  };

  // fused deconv: out[:, so] from hlds (= h(so+1)); residual frames[b][so+1]
  auto emit = [&](int so){
    int row = tid >> 4;                       // sample row 0..15
    int b = rowb + row;
    const float* fr = frames + ((size_t)b * 128 + so + 1) * 256;
    float* ob = out + ((size_t)b * T2 + so) * 256;
    #pragma unroll
    for (int e = 0; e < 2; e++){
      int pi = (tid & 15) * 2 + e;            // 0..31
      int pr = slc * 2 + (pi >> 4), pc = pi & 15;
      int ii = pr >> 2, pp = pr & 3, jj2 = pc >> 2, qq = pc & 3;
      float acc = dbias;
      #pragma unroll
      for (int c = 0; c < 32; c++){
        int ch = c * 16 + ii * 4 + jj2;
        acc += bf2f(hlds[HSWZ(row, ch >> 3) + (ch & 7)]) * dwl[c * 16 + pp * 4 + qq];
      }
      float dlt = tanhf(acc);
      float rv = fr[pr * 16 + pc] + dlt;
      ob[pr * 16 + pc] = fminf(fmaxf(rv, 0.0f), 1.0f);
    }
  };

  // prologue: gates(0) into gbuf[0]
  stagefeat(0);
  gatesgemm(0);

  for (int s = 0; s < T2; s++){
    // ---- shadow work: gates(s+1), off the inter-block dependency chain ----
    if (s + 1 < T2){
      __syncthreads();               // WAR: featl vs previous gatesgemm reads
      stagefeat(s + 1);              // ends with barrier
      gatesgemm((s + 1) & 1);
    }
    // ---- critical chain: r10 protocol verbatim ----
    poll(s);                         // barrier inside (also orders gbuf r/w)
    stage(s);
    f32x4 aR = {0.f,0.f,0.f,0.f}, aZ = {0.f,0.f,0.f,0.f}, aN = {0.f,0.f,0.f,0.f};
    #pragma unroll
    for (int kt = 0; kt < 16; kt++){
      us8 a = *(const us8*)&hlds[HSWZ(lr, kt * 4 + lh)];
      aR = mfma_bf16(a, wr[kt], aR);
      aZ = mfma_bf16(a, wz[kt], aZ);
      aN = mfma_bf16(a, wn[kt], aN);
    }
    const unsigned short* gb = &gbuf[s & 1][0];
    #pragma unroll
    for (int r = 0; r < 4; r++){
      float gxr = bf2f(gb[(      rloc + r) * 72 + w * 16 + lr]);
      float gxz = bf2f(gb[(16 + rloc + r) * 72 + w * 16 + lr]);
      float gxn = bf2f(gb[(32 + rloc + r) * 72 + w * 16 + lr]);
      float rr = sigm(gxr + aR[r] + bhr);
      float zz = sigm(gxz + aZ[r] + bhz);
      float nn = tanhf(gxn + rr * (aN[r] + bhn));
      float hv = (1.0f - zz) * nn + zz * hprev[r];
      hprev[r] = hv;
      hout[(rloc + r) * 64 + w * 16 + lr] = f2bf(hv);
    }
    __syncthreads();                 // hout ready
    if (tid < 128){
      int row = tid >> 3, q = tid & 7;
      u32x4 hv = *(const u32x4*)&hout[row * 64 + q * 8];
      u32x4* dst = hq + ((size_t)(((s + 1) & 1) * 512 + rowb + row) * 64 + slc * 8 + q);
      asm volatile("global_store_dwordx4 %0, %1, off sc0 sc1" :: "v"(dst), "v"(hv) : "memory");
    }
    asm volatile("s_waitcnt vmcnt(0)" ::: "memory");   // data drain (per wave)
    __syncthreads();                                   // all waves drained
    if (tid == 0){
      unsigned int tg = (unsigned)(s + 1);
      unsigned int* tp = tagbuf + (((size_t)((s + 1) & 1) * 8 + slc) * 32 + grp) * 16;
      asm volatile("global_store_dword %0, %1, off sc0 sc1" :: "v"(tp), "v"(tg) : "memory");
    }
    // fused deconv for out[:, s-1] — in the handoff shadow
    if (s >= 1) emit(s - 1);
  }
  // final output t=125 from h(126)
  poll(T2);                          // barrier also WAR-protects hlds vs last emit
  stage(T2);
  emit(T2 - 1);
}

extern "C" void kernel_launch(void* const* d_in, const int* in_sizes, int n_in,
                              void* d_out, int out_size, void* d_ws, size_t ws_size,
                              hipStream_t stream) {
  const float* frames   = (const float*)d_in[0];
  const float* conv_w   = (const float*)d_in[1];
  const float* conv_b   = (const float*)d_in[2];
  const float* w_ih     = (const float*)d_in[3];
  const float* w_hh     = (const float*)d_in[4];
  const float* b_ih     = (const float*)d_in[5];
  const float* b_hh     = (const float*)d_in[6];
  const float* deconv_w = (const float*)d_in[7];
  const float* deconv_b = (const float*)d_in[8];
  float* out = (float*)d_out;
  char* ws = (char*)d_ws;

  // workspace: wih_p 1.5M | whh_p 1.5M | hq 1M | tagbuf 32K | featg 66M (~70.3MB)
  unsigned short* wih_p  = (unsigned short*)(ws);
  unsigned short* whh_p  = (unsigned short*)(ws + 1572864LL);
  u32x4*          hq     = (u32x4*)         (ws + 3145728LL);
  unsigned int*   tagbuf = (unsigned int*)  (ws + 4194304LL);
  unsigned short* featg  = (unsigned short*)(ws + 4227072LL);

  pack_w_kernel<<<384, 256, 0, stream>>>(w_ih, wih_p);
  pack_w_kernel<<<384, 256, 0, stream>>>(w_hh, whh_p);
  scan_init_kernel<<<64, 256, 0, stream>>>(hq, tagbuf);
  conv_gelu_kernel<<<126 * 512, 256, 0, stream>>>(frames, conv_w, conv_b, featg);
  gru_scan_kernel<<<256, 256, 0, stream>>>(whh_p, wih_p, b_hh, b_ih, hq, tagbuf,
                                           featg, frames, deconv_w, deconv_b, out);
}

// Round 15
// 993.186 us; speedup vs baseline: 1.9247x; 1.0174x over previous
//
#include <hip/hip_runtime.h>
#include <cstdint>

typedef float f32x4 __attribute__((ext_vector_type(4)));
typedef __bf16 bf16x8 __attribute__((ext_vector_type(8)));
typedef unsigned short us8 __attribute__((ext_vector_type(8)));
typedef unsigned int u32x4 __attribute__((ext_vector_type(4)));

#define T2 126

__device__ __forceinline__ unsigned short f2bf(float x){
  union { float f; uint32_t u; } v; v.f = x;
  return (unsigned short)((v.u + 0x7fffu + ((v.u >> 16) & 1u)) >> 16);
}
__device__ __forceinline__ float bf2f(unsigned short h){
  union { uint32_t u; float f; } v; v.u = ((uint32_t)h) << 16; return v.f;
}
__device__ __forceinline__ f32x4 mfma_bf16(us8 a, us8 b, f32x4 c){
  return __builtin_amdgcn_mfma_f32_16x16x32_bf16(
      __builtin_bit_cast(bf16x8, a), __builtin_bit_cast(bf16x8, b), c, 0, 0, 0);
}
__device__ __forceinline__ float sigm(float x){ return 1.0f / (1.0f + __expf(-x)); }

// XOR-swizzled LDS address for a [rows][512] bf16 tile, 8-short (16B) chunks.
#define HSWZ(row, chunk) ((row) * 512 + ((((chunk) ^ ((row) & 7))) << 3))

// ---------------------------------------------------------------------------
// Pack (1536,512) fp32 weights -> bf16 MFMA B-fragments.
// ---------------------------------------------------------------------------
__global__ void __launch_bounds__(256) pack_w_kernel(const float* __restrict__ w,
                                                     unsigned short* __restrict__ dst){
  int tid = blockIdx.x * 256 + threadIdx.x;     // 0..98303
  int l = tid & 63;
  int tile = tid >> 6;                          // jt*16 + kt
  int kt = tile & 15, jt = tile >> 4;
  int row = jt * 16 + (l & 15);
  int col = kt * 32 + (l >> 4) * 8;
  const float* s = w + (size_t)row * 512 + col;
  unsigned short o[8];
  #pragma unroll
  for (int e = 0; e < 8; e++) o[e] = f2bf(s[e]);
  *(us8*)(dst + (size_t)tid * 8) = *(const us8*)o;
}

// ---------------------------------------------------------------------------
// Patchify conv + bias + exact GELU for ALL timesteps -> featg bf16
// layout [t][b][512]. erff lives here, off the scan chain.
// ---------------------------------------------------------------------------
__global__ void __launch_bounds__(256) conv_gelu_kernel(const float* __restrict__ frames,
                                                        const float* __restrict__ cw,
                                                        const float* __restrict__ cb,
                                                        unsigned short* __restrict__ featg){
  __shared__ float im[512];
  __shared__ float wl[1024];
  int n = blockIdx.x;              // t*512 + b
  int t = n >> 9, b = n & 511;
  const float* fr = frames + ((size_t)b * 128 + t) * 256;
  int tid = threadIdx.x;
  ((float2*)im)[tid] = ((const float2*)fr)[tid];   // frames t (prev) | t+1 (curr)
  #pragma unroll
  for (int i = 0; i < 4; i++) wl[tid + 256 * i] = cw[tid + 256 * i];
  __syncthreads();
  #pragma unroll
  for (int half = 0; half < 2; half++){
    int oi = tid + half * 256;
    int o = oi >> 4, ii = (oi >> 2) & 3, jj = oi & 3;
    const float* wc = &wl[o * 32];
    float s = cb[o];
    #pragma unroll
    for (int p = 0; p < 4; p++)
      #pragma unroll
      for (int q = 0; q < 4; q++){
        int pix = (ii * 4 + p) * 16 + jj * 4 + q;
        s += im[256 + pix] * wc[p * 4 + q] + im[pix] * wc[16 + p * 4 + q];
      }
    float g = 0.5f * s * (1.0f + erff(s * 0.70710678118654752f));
    featg[(size_t)n * 512 + oi] = f2bf(g);
  }
}

// ---------------------------------------------------------------------------
// Per-launch init: hq parity0 = h(0) = 0; all tags = 0.
// ---------------------------------------------------------------------------
__global__ void __launch_bounds__(256) scan_init_kernel(u32x4* __restrict__ hq,
                                                        unsigned int* __restrict__ tagbuf){
  int tid = blockIdx.x * 256 + threadIdx.x;
  int stride = gridDim.x * 256;
  for (int i = tid; i < 32768; i += stride)
    hq[i] = (u32x4){0u, 0u, 0u, 0u};
  for (int i = tid; i < 2 * 8 * 32 * 16; i += stride)
    tagbuf[i] = 0u;
}

// ---------------------------------------------------------------------------
// Weight-stationary persistent GRU scan + COUNTED-VMCNT shadow gates-GEMM.
// Grid = 256 blocks = 32 batch-groups (16 rows) x 8 hidden-slices (64 cols).
// Handoff = r10 protocol; the difference vs r14: shadow work is scheduled
// INSIDE the drain window. Loop: poll -> stage -> compute -> publish-issue
// -> feat(s+1)-load-issue -> vmcnt(4) (waits ONLY the older publish stores,
// feat loads stay in flight) -> barrier -> tag(s+1) -> vmcnt(0) -> featl
// write -> gates-GEMM(s+1) -> emit(s-1). Tag goes out one store-RT after
// compute (as r10); gemm+emit run in the consumers' observe-latency shadow.
// WAR/deadlock: tag(s+1) still proves stage(s) done (stage precedes tag
// in-iteration); gbuf[(s+1)&1] last read at compute(s-1); featl last read
// at gemm(s); both覆 covered by in-iteration barriers. No new dependency
// cycle (tags only ever wait on strictly older tags).
// ---------------------------------------------------------------------------
__global__ void __launch_bounds__(256, 1) gru_scan_kernel(
    const unsigned short* __restrict__ whh_p,
    const unsigned short* __restrict__ wih_p,
    const float* __restrict__ b_hh,
    const float* __restrict__ b_ih,
    u32x4* __restrict__ hq,                // [2][512][64] quads
    unsigned int* __restrict__ tagbuf,     // [2][8][32] x 16 u32 (64B stride)
    const unsigned short* __restrict__ featg,  // [126][512][512]
    const float* __restrict__ frames,
    const float* __restrict__ dw,
    const float* __restrict__ db,
    float* __restrict__ out){
  __shared__ unsigned short hlds[16 * 512];       // h(s) slab, swizzled
  __shared__ unsigned short featl[16 * 512];      // feat(s+1), swizzled
  __shared__ unsigned short gbuf[2][3 * 16 * 72]; // gates ping-pong (padded 72)
  __shared__ unsigned short hout[16 * 64];        // block's h(s+1) tile
  __shared__ float dwl[512];                      // deconv weights
  const int tid = threadIdx.x;
  const int B = blockIdx.x;
  const int grp = B & 31;                     // batch group 0..31
  const int slc = B >> 5;                     // hidden slice 0..7
  const int l = tid & 63;
  const int w = tid >> 6;                     // wave 0..3
  const int lr = l & 15, lh = l >> 4;
  const int j = slc * 64 + w * 16 + lr;       // hidden col
  const int rowb = grp * 16;                  // batch row base
  const int rloc = lh * 4;                    // + r = local row

  dwl[tid] = dw[tid]; dwl[tid + 256] = dw[tid + 256];
  const float dbias = db[0];

  // persistent w_hh fragments, pinned via volatile loads
  us8 wr[16], wz[16], wn[16];
  {
    const int jt = slc * 4 + w;
    #pragma unroll
    for (int kt = 0; kt < 16; kt++){
      wr[kt] = *(volatile const us8*)(whh_p + ((size_t)((jt      ) * 16 + kt) * 512 + l * 8));
      wz[kt] = *(volatile const us8*)(whh_p + ((size_t)((jt + 32) * 16 + kt) * 512 + l * 8));
      wn[kt] = *(volatile const us8*)(whh_p + ((size_t)((jt + 64) * 16 + kt) * 512 + l * 8));
    }
  }
  const float bhr = b_hh[j], bhz = b_hh[512 + j], bhn = b_hh[1024 + j];

  // shadow-gemm tile constants: wave w owns q = w*3..w*3+2 (gate gg, tile wtt)
  int jtg[3], gg[3], wtt[3]; float gbias[3];
  #pragma unroll
  for (int jj = 0; jj < 3; jj++){
    int q = w * 3 + jj; gg[jj] = q >> 2; wtt[jj] = q & 3;
    jtg[jj] = gg[jj] * 32 + slc * 4 + wtt[jj];
    gbias[jj] = b_ih[gg[jj] * 512 + slc * 64 + wtt[jj] * 16 + lr];
  }
  float hprev[4] = {0.0f, 0.0f, 0.0f, 0.0f};
  __syncthreads();                  // dwl ready

  // feat-load addressing (4 quads/thread from featg[u])
  const int fquad = tid & 63, fr0 = tid >> 6;

  // gates GEMM: featl (LDS) @ wih^T (L2-streamed) + b_ih -> gbuf[par]
  auto gatesgemm = [&](int par){
    f32x4 a0 = {0.f,0.f,0.f,0.f}, a1 = {0.f,0.f,0.f,0.f}, a2 = {0.f,0.f,0.f,0.f};
    #pragma unroll
    for (int kt = 0; kt < 16; kt++){
      us8 a = *(const us8*)&featl[HSWZ(lr, kt * 4 + lh)];
      us8 b0 = *(const us8*)(wih_p + ((size_t)(jtg[0] * 16 + kt) * 512 + l * 8));
      us8 b1 = *(const us8*)(wih_p + ((size_t)(jtg[1] * 16 + kt) * 512 + l * 8));
      us8 b2 = *(const us8*)(wih_p + ((size_t)(jtg[2] * 16 + kt) * 512 + l * 8));
      a0 = mfma_bf16(a, b0, a0);
      a1 = mfma_bf16(a, b1, a1);
      a2 = mfma_bf16(a, b2, a2);
    }
    unsigned short* gb = &gbuf[par][0];
    #pragma unroll
    for (int r = 0; r < 4; r++){
      gb[(gg[0] * 16 + lh * 4 + r) * 72 + wtt[0] * 16 + lr] = f2bf(a0[r] + gbias[0]);
      gb[(gg[1] * 16 + lh * 4 + r) * 72 + wtt[1] * 16 + lr] = f2bf(a1[r] + gbias[1]);
      gb[(gg[2] * 16 + lh * 4 + r) * 72 + wtt[2] * 16 + lr] = f2bf(a2[r] + gbias[2]);
    }
  };

  // poll 8 per-line tags for step s (parity s&1), then barrier
  auto poll = [&](int s){
    if (tid < 8){
      const unsigned int* tp = tagbuf + (((size_t)(s & 1) * 8 + tid) * 32 + grp) * 16;
      unsigned int want = (unsigned)s;
      unsigned int tv;
      for (;;){
        asm volatile("global_load_dword %0, %1, off sc0 sc1\n\ts_waitcnt vmcnt(0)"
                     : "=&v"(tv) : "v"(tp) : "memory");
        if (tv >= want) break;
        __builtin_amdgcn_s_sleep(1);
      }
    }
    __syncthreads();
  };

  // stage h(s) slab (16 rows x 64 quads) -> hlds, 4 quads/thread
  auto stage = [&](int s){
    const u32x4* rb = hq + (size_t)(s & 1) * 32768;
    const u32x4* p0 = rb + ((size_t)(rowb + fr0) * 64 + fquad);
    const u32x4* p1 = p0 + 4 * 64;
    const u32x4* p2 = p0 + 8 * 64;
    const u32x4* p3 = p0 + 12 * 64;
    u32x4 q0, q1, q2, q3;
    asm volatile(
      "global_load_dwordx4 %0, %4, off sc0 sc1\n\t"
      "global_load_dwordx4 %1, %5, off sc0 sc1\n\t"
      "global_load_dwordx4 %2, %6, off sc0 sc1\n\t"
      "global_load_dwordx4 %3, %7, off sc0 sc1\n\t"
      "s_waitcnt vmcnt(0)"
      : "=&v"(q0), "=&v"(q1), "=&v"(q2), "=&v"(q3)
      : "v"(p0), "v"(p1), "v"(p2), "v"(p3)
      : "memory");
    *(u32x4*)&hlds[HSWZ(fr0,      fquad)] = q0;
    *(u32x4*)&hlds[HSWZ(fr0 + 4,  fquad)] = q1;
    *(u32x4*)&hlds[HSWZ(fr0 + 8,  fquad)] = q2;
    *(u32x4*)&hlds[HSWZ(fr0 + 12, fquad)] = q3;
    __syncthreads();
  };

  // fused deconv: out[:, so] from hlds (= h(so+1)); residual frames[b][so+1]
  auto emit = [&](int so){
    int row = tid >> 4;                       // sample row 0..15
    int b = rowb + row;
    const float* fr = frames + ((size_t)b * 128 + so + 1) * 256;
    float* ob = out + ((size_t)b * T2 + so) * 256;
    #pragma unroll
    for (int e = 0; e < 2; e++){
      int pi = (tid & 15) * 2 + e;            // 0..31
      int pr = slc * 2 + (pi >> 4), pc = pi & 15;
      int ii = pr >> 2, pp = pr & 3, jj2 = pc >> 2, qq = pc & 3;
      float acc = dbias;
      #pragma unroll
      for (int c = 0; c < 32; c++){
        int ch = c * 16 + ii * 4 + jj2;
        acc += bf2f(hlds[HSWZ(row, ch >> 3) + (ch & 7)]) * dwl[c * 16 + pp * 4 + qq];
      }
      float dlt = tanhf(acc);
      float rv = fr[pr * 16 + pc] + dlt;
      ob[pr * 16 + pc] = fminf(fmaxf(rv, 0.0f), 1.0f);
    }
  };

  // prologue: feat(0) -> featl (plain loads) -> gates(0) into gbuf[0]
  {
    const u32x4* rb = (const u32x4*)featg;
    const u32x4* p0 = rb + ((size_t)(rowb + fr0) * 64 + fquad);
    u32x4 q0 = p0[0], q1 = p0[4 * 64], q2 = p0[8 * 64], q3 = p0[12 * 64];
    *(u32x4*)&featl[HSWZ(fr0,      fquad)] = q0;
    *(u32x4*)&featl[HSWZ(fr0 + 4,  fquad)] = q1;
    *(u32x4*)&featl[HSWZ(fr0 + 8,  fquad)] = q2;
    *(u32x4*)&featl[HSWZ(fr0 + 12, fquad)] = q3;
    __syncthreads();
    gatesgemm(0);
  }

  for (int s = 0; s < T2; s++){
    // ---- critical chain (r10) ----
    poll(s);                         // barrier inside (orders gbuf/featl WAR)
    stage(s);
    f32x4 aR = {0.f,0.f,0.f,0.f}, aZ = {0.f,0.f,0.f,0.f}, aN = {0.f,0.f,0.f,0.f};
    #pragma unroll
    for (int kt = 0; kt < 16; kt++){
      us8 a = *(const us8*)&hlds[HSWZ(lr, kt * 4 + lh)];
      aR = mfma_bf16(a, wr[kt], aR);
      aZ = mfma_bf16(a, wz[kt], aZ);
      aN = mfma_bf16(a, wn[kt], aN);
    }
    const unsigned short* gb = &gbuf[s & 1][0];
    #pragma unroll
    for (int r = 0; r < 4; r++){
      float gxr = bf2f(gb[(      rloc + r) * 72 + w * 16 + lr]);
      float gxz = bf2f(gb[(16 + rloc + r) * 72 + w * 16 + lr]);
      float gxn = bf2f(gb[(32 + rloc + r) * 72 + w * 16 + lr]);
      float rr = sigm(gxr + aR[r] + bhr);
      float zz = sigm(gxz + aZ[r] + bhz);
      float nn = tanhf(gxn + rr * (aN[r] + bhn));
      float hv = (1.0f - zz) * nn + zz * hprev[r];
      hprev[r] = hv;
      hout[(rloc + r) * 64 + w * 16 + lr] = f2bf(hv);
    }
    __syncthreads();                 // hout ready
    // publish h(s+1): 128 quad stores (issue only)
    if (tid < 128){
      int row = tid >> 3, q = tid & 7;
      u32x4 hv = *(const u32x4*)&hout[row * 64 + q * 8];
      u32x4* dst = hq + ((size_t)(((s + 1) & 1) * 512 + rowb + row) * 64 + slc * 8 + q);
      asm volatile("global_store_dwordx4 %0, %1, off sc0 sc1" :: "v"(dst), "v"(hv) : "memory");
    }
    // issue feat(s+1) loads (stay in flight across the counted wait)
    u32x4 f0, f1, f2, f3;
    const bool more = (s + 1 < T2);
    if (more){
      const u32x4* rb = (const u32x4*)(featg + (size_t)(s + 1) * 512 * 512);
      const u32x4* p0 = rb + ((size_t)(rowb + fr0) * 64 + fquad);
      const u32x4* p1 = p0 + 4 * 64;
      const u32x4* p2 = p0 + 8 * 64;
      const u32x4* p3 = p0 + 12 * 64;
      asm volatile(
        "global_load_dwordx4 %0, %4, off\n\t"
        "global_load_dwordx4 %1, %5, off\n\t"
        "global_load_dwordx4 %2, %6, off\n\t"
        "global_load_dwordx4 %3, %7, off"
        : "=&v"(f0), "=&v"(f1), "=&v"(f2), "=&v"(f3)
        : "v"(p0), "v"(p1), "v"(p2), "v"(p3)
        : "memory");
      // counted wait: publish stores (older) done; 4 feat loads still in flight
      asm volatile("s_waitcnt vmcnt(4)" ::: "memory");
    } else {
      asm volatile("s_waitcnt vmcnt(0)" ::: "memory");
    }
    __syncthreads();                 // all threads' publish stores drained
    if (tid == 0){
      unsigned int tg = (unsigned)(s + 1);
      unsigned int* tp = tagbuf + (((size_t)((s + 1) & 1) * 8 + slc) * 32 + grp) * 16;
      asm volatile("global_store_dword %0, %1, off sc0 sc1" :: "v"(tp), "v"(tg) : "memory");
    }
    // ---- shadow (overlaps consumers' tag-observe latency) ----
    if (more){
      asm volatile("s_waitcnt vmcnt(0)" ::: "memory");   // feat loads done
      __builtin_amdgcn_sched_barrier(0);
      *(u32x4*)&featl[HSWZ(fr0,      fquad)] = f0;
      *(u32x4*)&featl[HSWZ(fr0 + 4,  fquad)] = f1;
      *(u32x4*)&featl[HSWZ(fr0 + 8,  fquad)] = f2;
      *(u32x4*)&featl[HSWZ(fr0 + 12, fquad)] = f3;
      __syncthreads();               // featl ready
      gatesgemm((s + 1) & 1);
    }
    if (s >= 1) emit(s - 1);
  }
  // final output t=125 from h(126)
  poll(T2);                          // barrier also WAR-protects hlds vs last emit
  stage(T2);
  emit(T2 - 1);
}

extern "C" void kernel_launch(void* const* d_in, const int* in_sizes, int n_in,
                              void* d_out, int out_size, void* d_ws, size_t ws_size,
                              hipStream_t stream) {
  const float* frames   = (const float*)d_in[0];
  const float* conv_w   = (const float*)d_in[1];
  const float* conv_b   = (const float*)d_in[2];
  const float* w_ih     = (const float*)d_in[3];
  const float* w_hh     = (const float*)d_in[4];
  const float* b_ih     = (const float*)d_in[5];
  const float* b_hh     = (const float*)d_in[6];
  const float* deconv_w = (const float*)d_in[7];
  const float* deconv_b = (const float*)d_in[8];
  float* out = (float*)d_out;
  char* ws = (char*)d_ws;

  // workspace: wih_p 1.5M | whh_p 1.5M | hq 1M | tagbuf 32K | featg 66M (~70.3MB)
  unsigned short* wih_p  = (unsigned short*)(ws);
  unsigned short* whh_p  = (unsigned short*)(ws + 1572864LL);
  u32x4*          hq     = (u32x4*)         (ws + 3145728LL);
  unsigned int*   tagbuf = (unsigned int*)  (ws + 4194304LL);
  unsigned short* featg  = (unsigned short*)(ws + 4227072LL);

  pack_w_kernel<<<384, 256, 0, stream>>>(w_ih, wih_p);
  pack_w_kernel<<<384, 256, 0, stream>>>(w_hh, whh_p);
  scan_init_kernel<<<64, 256, 0, stream>>>(hq, tagbuf);
  conv_gelu_kernel<<<126 * 512, 256, 0, stream>>>(frames, conv_w, conv_b, featg);
  gru_scan_kernel<<<256, 256, 0, stream>>>(whh_p, wih_p, b_hh, b_ih, hq, tagbuf,
                                           featg, frames, deconv_w, deconv_b, out);
}